// Round 1
// baseline (6537.646 us; speedup 1.0000x reference)
//
#include <hip/hip_runtime.h>
#include <stdint.h>

#define EMB 64
#define BN_EPS 1e-5f
#define BSH 8              // bucket = 256 consecutive dst nodes
#define CHUNK 4096         // edges per part-chunk
#define TS 68              // fp32 LDS tile stride: 2-way max bank aliasing
#define ALS 72             // bf16 agg-row stride (144B): 2-way max aliasing
#define GRID 1024          // 4 blocks/CU x 256 CUs -- guaranteed co-resident
#define BLK 256

#define IN_F32    0
#define IN_BF16BN 2
#define IN_AGG    3

typedef short bfrag __attribute__((ext_vector_type(8)));   // 8 bf16 = 4 VGPRs
typedef float f32x4 __attribute__((ext_vector_type(4)));

union SM {
  struct {
    float tb[64 * TS];            // 17408 B
    float st[128];
    float scs[EMB];
    float shs[EMB];
    unsigned short aL[64 * ALS];  // 9216 B
  } mm;
  int hist[256];
  struct { int lcnt[256]; int lbase[256]; int loff[256]; } part;
  struct { int lcnt[256]; int a[256]; int lcur[256]; } bld;
  int scan[256];
};

__device__ __forceinline__ unsigned short f2b(float x) {
  unsigned u = __float_as_uint(x);
  u += 0x7FFFu + ((u >> 16) & 1u);   // round-to-nearest-even
  return (unsigned short)(u >> 16);
}
__device__ __forceinline__ float b2f(unsigned short v) {
  return __uint_as_float(((unsigned)v) << 16);
}

// ---- monotonic device-scope grid barrier (no reset; bar memset per launch) --
__device__ __forceinline__ void gsync(unsigned int* bar, unsigned int target) {
  __syncthreads();
  if (threadIdx.x == 0) {
    __threadfence();   // agent-scope release of all prior block writes
    __hip_atomic_fetch_add(bar, 1u, __ATOMIC_ACQ_REL, __HIP_MEMORY_SCOPE_AGENT);
    while (__hip_atomic_load(bar, __ATOMIC_ACQUIRE, __HIP_MEMORY_SCOPE_AGENT) < target)
      __builtin_amdgcn_s_sleep(2);
  }
  __syncthreads();
}

// ---------------- stage: weight transpose + zero init ----------------------
__device__ void stage_prep(const float* ae_w, const float* W1, const float* W2,
                           unsigned short* Wt16, int* bcnt, float* stats, int L) {
  const int tid = threadIdx.x;
  const int nw = (1 + 2 * L) * EMB * EMB;
  for (int gid = blockIdx.x * BLK + tid; gid < nw; gid += GRID * BLK) {
    int mI = gid >> 12;
    int j = (gid >> 6) & 63;
    int k = gid & 63;
    const float* srcw = (mI == 0) ? ae_w
                      : (mI <= L ? W1 + (size_t)(mI - 1) * EMB * EMB
                                 : W2 + (size_t)(mI - 1 - L) * EMB * EMB);
    Wt16[gid] = f2b(srcw[k * EMB + j]);   // Wt[m][j][k] = W[k][j]
  }
  const int nstats = L * 2 * 8 * 128;
  for (int i = blockIdx.x * BLK + tid; i < nstats; i += GRID * BLK) stats[i] = 0.f;
  if (blockIdx.x == GRID - 1) bcnt[tid] = 0;
}

// ---------------- stage: bucket histogram ----------------------------------
__device__ void stage_hist(SM* sm, const int* ei, int* bcnt, int E, int nb) {
  const int tid = threadIdx.x;
  sm->hist[tid] = 0;
  __syncthreads();
  for (int e = blockIdx.x * BLK + tid; e < E; e += GRID * BLK)
    atomicAdd(&sm->hist[((unsigned)ei[E + e]) >> BSH], 1);
  __syncthreads();
  if (tid < nb && sm->hist[tid]) atomicAdd(&bcnt[tid], sm->hist[tid]);
  __syncthreads();   // LDS union handed to encoder next
}

// ---------------- stage: bucket scan (block 0) ------------------------------
__device__ void stage_scan(SM* sm, const int* bcnt, int* bbase, int* bcur, int nb) {
  if (blockIdx.x != 0) return;
  const int t = threadIdx.x;
  int v = (t < nb) ? bcnt[t] : 0;
  sm->scan[t] = v;
  __syncthreads();
  for (int off = 1; off < 256; off <<= 1) {
    int x2 = (t >= off) ? sm->scan[t - off] : 0;
    __syncthreads();
    sm->scan[t] += x2;
    __syncthreads();
  }
  int excl = sm->scan[t] - v;
  if (t < nb) { bbase[t] = excl; bcur[t] = excl; }
  if (t == nb - 1) bbase[nb] = sm->scan[t];
}

// ---------------- stage: compact edges into per-bucket runs ----------------
__device__ void stage_part(SM* sm, const int* ei, const float* ew,
                           int* bcur, int2* eG, int E) {
  const int tid = threadIdx.x;
  for (int c0 = blockIdx.x * CHUNK; c0 < E; c0 += GRID * CHUNK) {
    sm->part.lcnt[tid] = 0;
    __syncthreads();
    int src[16], pk[16], g[16];
    float wt[16];
#pragma unroll
    for (int i = 0; i < 16; i++) {
      int e = c0 + i * 256 + tid;
      if (e < E) {
        int d = ei[E + e];
        src[i] = ei[e];
        wt[i] = ew[e];
        g[i] = ((unsigned)d) >> BSH;
        pk[i] = src[i] | ((d & 255) << 24);
        atomicAdd(&sm->part.lcnt[g[i]], 1);
      } else g[i] = -1;
    }
    __syncthreads();
    if (sm->part.lcnt[tid]) sm->part.lbase[tid] = atomicAdd(&bcur[tid], sm->part.lcnt[tid]);
    sm->part.loff[tid] = 0;
    __syncthreads();
#pragma unroll
    for (int i = 0; i < 16; i++) {
      if (g[i] >= 0) {
        int pos = sm->part.lbase[g[i]] + atomicAdd(&sm->part.loff[g[i]], 1);
        eG[pos] = make_int2(pk[i], __float_as_int(wt[i]));
      }
    }
    __syncthreads();
  }
}

// ---------------- stage: exact CSR inside each bucket ----------------------
__device__ void stage_build(SM* sm, const int2* eG, const int* bbase,
                            int* rowst, int* counts, int2* pairs, int N, int nbuck) {
  const int t = threadIdx.x;
  for (int b = blockIdx.x; b < nbuck; b += GRID) {
    const int e0 = bbase[b], e1 = bbase[b + 1];
    sm->bld.lcnt[t] = 0;
    __syncthreads();
    for (int i = e0 + t; i < e1; i += 256)
      atomicAdd(&sm->bld.lcnt[((unsigned)eG[i].x) >> 24], 1);
    __syncthreads();
    int v = sm->bld.lcnt[t];
    sm->bld.a[t] = v;
    __syncthreads();
    for (int off = 1; off < 256; off <<= 1) {
      int x2 = (t >= off) ? sm->bld.a[t - off] : 0;
      __syncthreads();
      sm->bld.a[t] += x2;
      __syncthreads();
    }
    int excl = sm->bld.a[t] - v;
    sm->bld.lcur[t] = excl;
    int node = (b << BSH) + t;
    if (node < N) { rowst[node] = e0 + excl; counts[node] = v; }
    __syncthreads();
    for (int i = e0 + t; i < e1; i += 256) {
      int2 p = eG[i];
      int loc = ((unsigned)p.x) >> 24;
      int pos = e0 + atomicAdd(&sm->bld.lcur[loc], 1);
      pairs[pos] = make_int2(p.x & 0x00FFFFFF, p.y);
    }
    __syncthreads();
  }
}

// ---------------- 64-node tile: (optional gather) + MFMA matmul ------------
// IN_F32: fp32 rows -> bf16.  IN_BF16BN: bf16 rows -> BN+relu.  IN_AGG:
// gather (agg + self) into LDS bf16 rows, then matmul.  Stats (sum/sumsq of
// fp32-exact output) atomically spread over 8 copies keyed by tile&7.
template <int INMODE, bool DO_STATS>
__device__ void mm_tile(SM* sm, int tile,
    const void* in_v, const unsigned short* Wt, const float* bias,
    const float* stats_in, const float* g, const float* be, float invN,
    unsigned short* out16, float* st_out,
    const unsigned short* hb, const int* rowst, const int* counts,
    const int2* pairs, int N) {
  const int tid = threadIdx.x;
  const int lane = tid & 63;
  const int wv = tid >> 6;
  const int node0 = tile * 64;
  const int m = lane & 15;
  const int quad = lane >> 4;

  if (DO_STATS && tid < 128) sm->mm.st[tid] = 0.f;
  if (INMODE == IN_BF16BN && tid < EMB) {
    float s1 = 0.f, s2 = 0.f;
#pragma unroll
    for (int k = 0; k < 8; k++) {
      s1 += stats_in[k * 128 + tid];
      s2 += stats_in[k * 128 + 64 + tid];
    }
    float mu = s1 * invN;
    float va = fmaf(s2, invN, -mu * mu);
    float rs = rsqrtf(va + BN_EPS);
    float sc = rs * g[tid];
    sm->mm.scs[tid] = sc;
    sm->mm.shs[tid] = fmaf(-mu, sc, be[tid]);
  }
  if (INMODE == IN_AGG) {
    // each wave gathers its own 16 A-rows; 2 nodes x 8 slots = 16 loads deep
#pragma unroll 1
    for (int i = 0; i < 16; i += 2) {
      const int rA = wv * 16 + i;
      const int nA = node0 + rA, nB = nA + 1;
      int sA = 0, eA = 0, sB = 0, eB = 0;
      if (nA < N) { sA = rowst[nA]; eA = sA + counts[nA]; }
      if (nB < N) { sB = rowst[nB]; eB = sB + counts[nB]; }
      float accA[8] = {0, 0, 0, 0, 0, 0, 0, 0};
      float accB[8] = {0, 0, 0, 0, 0, 0, 0, 0};
      for (int xA = sA, xB = sB; (xA < eA) | (xB < eB); xA += 8, xB += 8) {
        int2 pA[8], pB[8];
        float wA[8], wB[8];
#pragma unroll
        for (int k2 = 0; k2 < 8; k2++) {
          int ia = xA + k2;
          bool oa = ia < eA;
          int2 p = pairs[oa ? ia : 0];
          pA[k2] = p;
          wA[k2] = oa ? __int_as_float(p.y) : 0.f;
        }
#pragma unroll
        for (int k2 = 0; k2 < 8; k2++) {
          int ib = xB + k2;
          bool ob = ib < eB;
          int2 p = pairs[ob ? ib : 0];
          pB[k2] = p;
          wB[k2] = ob ? __int_as_float(p.y) : 0.f;
        }
#pragma unroll
        for (int k2 = 0; k2 < 8; k2++)
          accA[k2] = fmaf(wA[k2], b2f(hb[(size_t)pA[k2].x * EMB + lane]), accA[k2]);
#pragma unroll
        for (int k2 = 0; k2 < 8; k2++)
          accB[k2] = fmaf(wB[k2], b2f(hb[(size_t)pB[k2].x * EMB + lane]), accB[k2]);
      }
      float sA8 = (((accA[0] + accA[1]) + (accA[2] + accA[3])) +
                   ((accA[4] + accA[5]) + (accA[6] + accA[7])));
      float sB8 = (((accB[0] + accB[1]) + (accB[2] + accB[3])) +
                   ((accB[4] + accB[5]) + (accB[6] + accB[7])));
      if (nA < N) sA8 += b2f(hb[(size_t)nA * EMB + lane]);
      if (nB < N) sB8 += b2f(hb[(size_t)nB * EMB + lane]);
      sm->mm.aL[rA * ALS + lane] = f2b(nA < N ? sA8 : 0.f);
      sm->mm.aL[(rA + 1) * ALS + lane] = f2b(nB < N ? sB8 : 0.f);
    }
  }
  __syncthreads();   // st zero / scs / aL all published

  // A fragments (2 K-steps)
  bfrag a0 = {0, 0, 0, 0, 0, 0, 0, 0}, a1 = {0, 0, 0, 0, 0, 0, 0, 0};
  if (INMODE == IN_AGG) {
    const unsigned short* ab = &sm->mm.aL[(wv * 16 + m) * ALS + quad * 8];
    a0 = *(const bfrag*)ab;
    a1 = *(const bfrag*)(ab + 32);
  } else {
    const int arow = node0 + wv * 16 + m;
    if (arow < N) {
      if (INMODE == IN_BF16BN) {
        const unsigned short* ab =
            (const unsigned short*)in_v + (size_t)arow * EMB + quad * 8;
        bfrag r0 = *(const bfrag*)ab;
        bfrag r1 = *(const bfrag*)(ab + 32);
#pragma unroll
        for (int j = 0; j < 8; j++) {
          int k0 = quad * 8 + j;
          float v0 = b2f((unsigned short)r0[j]);
          float v1 = b2f((unsigned short)r1[j]);
          v0 = fmaxf(0.f, fmaf(v0, sm->mm.scs[k0], sm->mm.shs[k0]));
          v1 = fmaxf(0.f, fmaf(v1, sm->mm.scs[k0 + 32], sm->mm.shs[k0 + 32]));
          a0[j] = (short)f2b(v0);
          a1[j] = (short)f2b(v1);
        }
      } else {   // IN_F32
        const float* af = (const float*)in_v + (size_t)arow * EMB + quad * 8;
#pragma unroll
        for (int j = 0; j < 8; j++) {
          a0[j] = (short)f2b(af[j]);
          a1[j] = (short)f2b(af[32 + j]);
        }
      }
    }
  }

  // B fragments (transposed bf16 weights, L2-hot) + MFMA
  const unsigned short* bb = Wt + (size_t)m * EMB + quad * 8;
  f32x4 acc[4];
#pragma unroll
  for (int c = 0; c < 4; c++) {
    bfrag b0 = *(const bfrag*)(bb + c * 16 * EMB);
    bfrag b1 = *(const bfrag*)(bb + c * 16 * EMB + 32);
    f32x4 z = {0.f, 0.f, 0.f, 0.f};
    z = __builtin_amdgcn_mfma_f32_16x16x32_bf16(a0, b0, z, 0, 0, 0);
    z = __builtin_amdgcn_mfma_f32_16x16x32_bf16(a1, b1, z, 0, 0, 0);
    acc[c] = z;
  }

  // epilogue: bias + fp32 LDS tile (invalid rows -> 0 so stats stay clean)
#pragma unroll
  for (int c = 0; c < 4; c++) {
    float bj = bias[c * 16 + m];
#pragma unroll
    for (int r = 0; r < 4; r++) {
      int row = wv * 16 + quad * 4 + r;
      float v = (node0 + row < N) ? (acc[c][r] + bj) : 0.f;
      sm->mm.tb[row * TS + c * 16 + m] = v;
    }
  }
  __syncthreads();

  if (DO_STATS) {
    float ssum = 0.f, ssq = 0.f;
#pragma unroll
    for (int i = 0; i < 16; i++) {
      float v = sm->mm.tb[(wv * 16 + i) * TS + lane];
      ssum += v;
      ssq = fmaf(v, v, ssq);
    }
    atomicAdd(&sm->mm.st[lane], ssum);
    atomicAdd(&sm->mm.st[64 + lane], ssq);
  }

  // coalesced bf16 flush
  ushort4* o4 = (ushort4*)(out16 + (size_t)node0 * EMB);
#pragma unroll
  for (int it = 0; it < 4; it++) {
    int flat4 = it * 256 + tid;
    int nsub = flat4 >> 4;
    int c4 = flat4 & 15;
    if (node0 + nsub < N) {
      const float* s4 = sm->mm.tb + nsub * TS + c4 * 4;
      ushort4 o;
      o.x = f2b(s4[0]); o.y = f2b(s4[1]);
      o.z = f2b(s4[2]); o.w = f2b(s4[3]);
      o4[flat4] = o;
    }
  }

  if (DO_STATS) {
    __syncthreads();
    if (tid < 128)
      atomicAdd(&st_out[((unsigned)tile & 7u) * 128 + tid], sm->mm.st[tid]);
  }
  __syncthreads();
}

// ---------------- stage: outer BN + relu + residual ------------------------
__device__ void stage_bnres(SM* sm, const unsigned short* u16, const float* st,
                            const float* g, const float* be,
                            unsigned short* hb16, float* out32,
                            float invN, int total4, bool last) {
  const int tid = threadIdx.x;
  if (tid < EMB) {
    float s1 = 0.f, s2 = 0.f;
#pragma unroll
    for (int k = 0; k < 8; k++) {
      s1 += st[k * 128 + tid];
      s2 += st[k * 128 + 64 + tid];
    }
    float mu = s1 * invN;
    float va = fmaf(s2, invN, -mu * mu);
    float rs = rsqrtf(va + BN_EPS);
    float sc = rs * g[tid];
    sm->mm.scs[tid] = sc;
    sm->mm.shs[tid] = fmaf(-mu, sc, be[tid]);
  }
  __syncthreads();
  for (int i4 = blockIdx.x * BLK + tid; i4 < total4; i4 += GRID * BLK) {
    int c4 = i4 & 15;
    ushort4 uv = ((const ushort4*)u16)[i4];
    ushort4 hv = ((const ushort4*)hb16)[i4];
    float4 scv = *(const float4*)&sm->mm.scs[c4 * 4];
    float4 shv = *(const float4*)&sm->mm.shs[c4 * 4];
    float4 o;
    o.x = fmaxf(0.f, fmaf(b2f(uv.x), scv.x, shv.x)) + b2f(hv.x);
    o.y = fmaxf(0.f, fmaf(b2f(uv.y), scv.y, shv.y)) + b2f(hv.y);
    o.z = fmaxf(0.f, fmaf(b2f(uv.z), scv.z, shv.z)) + b2f(hv.z);
    o.w = fmaxf(0.f, fmaf(b2f(uv.w), scv.w, shv.w)) + b2f(hv.w);
    if (last) {
      ((float4*)out32)[i4] = o;
    } else {
      ushort4 ob;
      ob.x = f2b(o.x); ob.y = f2b(o.y);
      ob.z = f2b(o.z); ob.w = f2b(o.w);
      ((ushort4*)hb16)[i4] = ob;
    }
  }
  __syncthreads();
}

// ---------------- the persistent kernel ------------------------------------
__global__ void __launch_bounds__(BLK, 4) mega(
    const float* __restrict__ x, const int* __restrict__ ei,
    const float* __restrict__ ew, const float* __restrict__ ae_w,
    const float* __restrict__ ae_b, const float* __restrict__ W1,
    const float* __restrict__ b1, const float* __restrict__ g1,
    const float* __restrict__ be1, const float* __restrict__ W2,
    const float* __restrict__ b2, const float* __restrict__ g_out,
    const float* __restrict__ be_out,
    unsigned short* hb16, unsigned short* b16a, unsigned short* t16,
    unsigned short* Wt16, int* counts, int* rowst,
    int* bcnt, int* bbase, int* bcur, int2* pairs, int2* eG,
    float* stats, unsigned int* bar, float* out32, int N, int E, int L) {
  __shared__ SM sm;
  const float invN = 1.0f / (float)N;
  const int nbuck = (N + 255) >> BSH;
  const int ntiles = (N + 63) >> 6;
  unsigned int gen = 0;

  stage_prep(ae_w, W1, W2, Wt16, bcnt, stats, L);
  gsync(bar, ++gen * GRID);

  stage_hist(&sm, ei, bcnt, E, nbuck);
  for (int t = blockIdx.x; t < ntiles; t += GRID)
    mm_tile<IN_F32, false>(&sm, t, x, Wt16, ae_b, nullptr, nullptr, nullptr,
                           invN, hb16, nullptr, nullptr, nullptr, nullptr,
                           nullptr, N);
  gsync(bar, ++gen * GRID);

  stage_scan(&sm, bcnt, bbase, bcur, nbuck);
  gsync(bar, ++gen * GRID);

  stage_part(&sm, ei, ew, bcur, eG, E);
  gsync(bar, ++gen * GRID);

  stage_build(&sm, eG, bbase, rowst, counts, pairs, N, nbuck);
  gsync(bar, ++gen * GRID);

  for (int l = 0; l < L; l++) {
    float* st1 = stats + (size_t)(l * 2 + 0) * 1024;
    float* st2 = stats + (size_t)(l * 2 + 1) * 1024;

    for (int t = blockIdx.x; t < ntiles; t += GRID)
      mm_tile<IN_AGG, true>(&sm, t, nullptr,
                            Wt16 + (size_t)(1 + l) * EMB * EMB,
                            b1 + (size_t)l * EMB, nullptr, nullptr, nullptr,
                            invN, t16, st1, hb16, rowst, counts, pairs, N);
    gsync(bar, ++gen * GRID);

    for (int t = blockIdx.x; t < ntiles; t += GRID)
      mm_tile<IN_BF16BN, true>(&sm, t, t16,
                               Wt16 + (size_t)(1 + L + l) * EMB * EMB,
                               b2 + (size_t)l * EMB, st1,
                               g1 + (size_t)l * EMB, be1 + (size_t)l * EMB,
                               invN, b16a, st2, nullptr, nullptr, nullptr,
                               nullptr, N);
    gsync(bar, ++gen * GRID);

    stage_bnres(&sm, b16a, st2, g_out + (size_t)l * EMB,
                be_out + (size_t)l * EMB, hb16, out32, invN, N * 16,
                l == L - 1);
    if (l != L - 1) gsync(bar, ++gen * GRID);
  }
}

// ---------------- launcher ----------------
extern "C" void kernel_launch(void* const* d_in, const int* in_sizes, int n_in,
                              void* d_out, int out_size, void* d_ws, size_t ws_size,
                              hipStream_t stream) {
  const float* x     = (const float*)d_in[0];
  const int*   ei    = (const int*)d_in[1];
  const float* ew    = (const float*)d_in[3];
  const float* ae_w  = (const float*)d_in[4];
  const float* ae_b  = (const float*)d_in[5];
  const float* W1    = (const float*)d_in[6];
  const float* b1    = (const float*)d_in[7];
  const float* g1    = (const float*)d_in[8];
  const float* be1   = (const float*)d_in[9];
  const float* W2    = (const float*)d_in[10];
  const float* b2    = (const float*)d_in[11];
  const float* g_out = (const float*)d_in[12];
  const float* be_out= (const float*)d_in[13];

  const int N = in_sizes[0] / EMB;
  const int E = in_sizes[3];
  const int L = in_sizes[6] / (EMB * EMB);

  uintptr_t p = (uintptr_t)d_ws;
  auto alloc = [&](size_t bytes) -> void* {
    p = (p + 255) & ~(uintptr_t)255;
    void* r = (void*)p;
    p += bytes;
    return r;
  };
  unsigned short* hb16 = (unsigned short*)alloc((size_t)N * EMB * 2);
  unsigned short* b16a = (unsigned short*)alloc((size_t)N * EMB * 2);
  unsigned short* t16  = (unsigned short*)alloc((size_t)N * EMB * 2);
  unsigned short* Wt16 = (unsigned short*)alloc((size_t)(1 + 2 * L) * EMB * EMB * 2);
  int*   counts= (int*)alloc((size_t)N * 4);
  int*   rowst = (int*)alloc((size_t)N * 4);
  int*   bcnt  = (int*)alloc(256 * 4);
  int*   bbase = (int*)alloc(257 * 4);
  int*   bcur  = (int*)alloc(256 * 4);
  int2*  pairs = (int2*)alloc((size_t)E * 8);
  int2*  eG    = (int2*)alloc((size_t)E * 8);
  float* stats = (float*)alloc((size_t)L * 2 * 8 * 128 * 4);
  unsigned int* bar = (unsigned int*)alloc(256);
  (void)ws_size; (void)n_in; (void)out_size;

  hipMemsetAsync(bar, 0, 256, stream);

  hipLaunchKernelGGL(mega, dim3(GRID), dim3(BLK), 0, stream,
                     x, ei, ew, ae_w, ae_b, W1, b1, g1, be1, W2, b2,
                     g_out, be_out,
                     hb16, b16a, t16, Wt16, counts, rowst,
                     bcnt, bbase, bcur, pairs, eG,
                     stats, bar, (float*)d_out, N, E, L);
}

// Round 2
// 403.733 us; speedup vs baseline: 16.1930x; 16.1930x over previous
//
#include <hip/hip_runtime.h>
#include <stdint.h>

#define EMB 64
#define BN_EPS 1e-5f
#define BSH 8              // bucket = 256 consecutive dst nodes
#define CHUNK 4096         // edges per k_part block
#define TS 68              // LDS tile stride (floats): 2-way max bank aliasing
#define NHB 120            // histogram partial blocks

typedef short bfrag __attribute__((ext_vector_type(8)));   // 8 bf16 = 4 VGPRs
typedef float f32x4 __attribute__((ext_vector_type(4)));

#define IN_F32    0
#define IN_BF16   1
#define IN_BF16BN 2

__device__ __forceinline__ unsigned short f2b(float x) {
    unsigned u = __float_as_uint(x);
    u += 0x7FFFu + ((u >> 16) & 1u);   // round-to-nearest-even
    return (unsigned short)(u >> 16);
}
__device__ __forceinline__ float b2f(unsigned short v) {
    return __uint_as_float(((unsigned)v) << 16);
}

// ---- prep: weights -> transposed bf16, zero stats, per-block hist partials --
__global__ void __launch_bounds__(256) k_prep_hist(
        const float* __restrict__ ae_w, const float* __restrict__ W1,
        const float* __restrict__ W2, unsigned short* __restrict__ Wt16,
        int* __restrict__ hist_part, float* __restrict__ stats,
        const int* __restrict__ ei, int E, int L, int nstats) {
    __shared__ int lh[256];
    const int tid = threadIdx.x;
    const int nw = (1 + 2 * L) * EMB * EMB;
    for (int gid = blockIdx.x * 256 + tid; gid < nw; gid += gridDim.x * 256) {
        int m = gid >> 12;
        int j = (gid >> 6) & 63;   // output col
        int k = gid & 63;          // input feature
        const float* src = (m == 0) ? ae_w
                         : (m <= L ? W1 + (size_t)(m - 1) * EMB * EMB
                                   : W2 + (size_t)(m - 1 - L) * EMB * EMB);
        Wt16[gid] = f2b(src[k * EMB + j]);   // Wt[m][j][k] = W[k][j]
    }
    for (int i = blockIdx.x * 256 + tid; i < nstats; i += gridDim.x * 256)
        stats[i] = 0.0f;
    if (blockIdx.x < NHB) {
        lh[tid] = 0;
        __syncthreads();
        for (int e = blockIdx.x * 256 + tid; e < E; e += NHB * 256)
            atomicAdd(&lh[((unsigned)ei[E + e]) >> BSH], 1);
        __syncthreads();
        hist_part[blockIdx.x * 256 + tid] = lh[tid];   // no global atomics
    }
}

// ---------------- single-block bucket scan (sums partials) ----------------
__global__ void __launch_bounds__(256) k_bscan(const int* __restrict__ hist_part,
                                               int* __restrict__ bbase,
                                               int* __restrict__ bcur, int nb) {
    __shared__ int a[256];
    const int t = threadIdx.x;
    int v = 0;
    for (int b = 0; b < NHB; b++) v += hist_part[b * 256 + t];
    a[t] = v;
    __syncthreads();
    for (int off = 1; off < 256; off <<= 1) {
        int x = (t >= off) ? a[t - off] : 0;
        __syncthreads();
        a[t] += x;
        __syncthreads();
    }
    int excl = a[t] - v;
    if (t < nb) { bbase[t] = excl; bcur[t] = excl; }
    if (t == nb - 1) bbase[nb] = a[t];
}

// ---------------- phase 1: compact edges into per-bucket runs --------------
__global__ void __launch_bounds__(256) k_part(
        const int* __restrict__ ei, const float* __restrict__ ew,
        int* __restrict__ bcur, int2* __restrict__ eG, int E) {
    __shared__ int lcnt[256], lbase[256], loff[256];
    const int tid = threadIdx.x;
    const int c0 = blockIdx.x * CHUNK;
    lcnt[tid] = 0;
    __syncthreads();
    int src[16], pk[16], g[16];
    float wt[16];
#pragma unroll
    for (int i = 0; i < 16; i++) {
        int e = c0 + i * 256 + tid;
        if (e < E) {
            int d = ei[E + e];
            src[i] = ei[e];
            wt[i] = ew[e];
            g[i] = ((unsigned)d) >> BSH;
            pk[i] = src[i] | ((d & 255) << 24);
            atomicAdd(&lcnt[g[i]], 1);
        } else g[i] = -1;
    }
    __syncthreads();
    if (lcnt[tid]) lbase[tid] = atomicAdd(&bcur[tid], lcnt[tid]);
    loff[tid] = 0;
    __syncthreads();
#pragma unroll
    for (int i = 0; i < 16; i++) {
        if (g[i] >= 0) {
            int pos = lbase[g[i]] + atomicAdd(&loff[g[i]], 1);
            eG[pos] = make_int2(pk[i], __float_as_int(wt[i]));
        }
    }
}

// ---------------- phase 2: exact CSR inside each bucket --------------------
__global__ void __launch_bounds__(256) k_build(
        const int2* __restrict__ eG, const int* __restrict__ bbase,
        int* __restrict__ rowst, int* __restrict__ counts,
        int2* __restrict__ pairs, int N) {
    __shared__ int lcnt[256], a[256], lcur[256];
    const int t = threadIdx.x;
    const int b = blockIdx.x;
    const int e0 = bbase[b], e1 = bbase[b + 1];
    lcnt[t] = 0;
    __syncthreads();
    for (int i = e0 + t; i < e1; i += 256)
        atomicAdd(&lcnt[((unsigned)eG[i].x) >> 24], 1);
    __syncthreads();
    int v = lcnt[t];
    a[t] = v;
    __syncthreads();
    for (int off = 1; off < 256; off <<= 1) {
        int x = (t >= off) ? a[t - off] : 0;
        __syncthreads();
        a[t] += x;
        __syncthreads();
    }
    int excl = a[t] - v;
    lcur[t] = excl;
    int node = (b << BSH) + t;
    if (node < N) { rowst[node] = e0 + excl; counts[node] = v; }
    __syncthreads();
    for (int i = e0 + t; i < e1; i += 256) {
        int2 p = eG[i];
        int loc = ((unsigned)p.x) >> 24;
        int pos = e0 + atomicAdd(&lcur[loc], 1);
        pairs[pos] = make_int2(p.x & 0x00FFFFFF, p.y);
    }
}

// ---- aggregation: wave handles TWO nodes interleaved -> 16 loads in flight --
__global__ void k_agg(const unsigned short* __restrict__ hb,
                      const int* __restrict__ rowst,
                      const int* __restrict__ counts, const int2* __restrict__ pairs,
                      unsigned short* __restrict__ out16, int N) {
    const int lane = threadIdx.x & 63;
    int wave = (blockIdx.x * blockDim.x + threadIdx.x) >> 6;
    const int nwaves = (gridDim.x * blockDim.x) >> 6;
    for (int nA = wave; nA < N; nA += 2 * nwaves) {
        const int nB = nA + nwaves;
        const int uA = __builtin_amdgcn_readfirstlane(nA);
        const int uB = __builtin_amdgcn_readfirstlane(nB);
        const bool hasB = uB < N;
        int sA = rowst[uA], eA = sA + counts[uA];
        int sB = 0, eB = 0;
        if (hasB) { sB = rowst[uB]; eB = sB + counts[uB]; }
        float aA[8] = {0, 0, 0, 0, 0, 0, 0, 0};
        float aB[8] = {0, 0, 0, 0, 0, 0, 0, 0};
        for (int xA = sA, xB = sB; (xA < eA) | (xB < eB); xA += 8, xB += 8) {
            int2 pA[8], pB[8];
            float wA[8], wB[8];
#pragma unroll
            for (int k = 0; k < 8; k++) {
                int i = xA + k;
                bool ok = i < eA;
                int2 p = pairs[ok ? i : 0];
                pA[k] = p;
                wA[k] = ok ? __int_as_float(p.y) : 0.f;
            }
#pragma unroll
            for (int k = 0; k < 8; k++) {
                int i = xB + k;
                bool ok = i < eB;
                int2 p = pairs[ok ? i : 0];
                pB[k] = p;
                wB[k] = ok ? __int_as_float(p.y) : 0.f;
            }
#pragma unroll
            for (int k = 0; k < 8; k++)
                aA[k] = fmaf(wA[k], b2f(hb[(size_t)pA[k].x * EMB + lane]), aA[k]);
#pragma unroll
            for (int k = 0; k < 8; k++)
                aB[k] = fmaf(wB[k], b2f(hb[(size_t)pB[k].x * EMB + lane]), aB[k]);
        }
        float sumA = (((aA[0] + aA[1]) + (aA[2] + aA[3])) +
                      ((aA[4] + aA[5]) + (aA[6] + aA[7]))) +
                     b2f(hb[(size_t)uA * EMB + lane]);
        out16[(size_t)uA * EMB + lane] = f2b(sumA);
        if (hasB) {
            float sumB = (((aB[0] + aB[1]) + (aB[2] + aB[3])) +
                          ((aB[4] + aB[5]) + (aB[6] + aB[7]))) +
                         b2f(hb[(size_t)uB * EMB + lane]);
            out16[(size_t)uB * EMB + lane] = f2b(sumB);
        }
    }
}

// ---------------- MFMA matmul: block = 64-node tile, 4 waves ---------------
// Stats spread over 8 global copies (blockIdx&7) to cut atomic contention;
// consumers sum the 8 copies.
template <int INMODE, bool DO_STATS>
__global__ void __launch_bounds__(256) k_mmx(
        const void* __restrict__ in_v, const unsigned short* __restrict__ Wt,
        const float* __restrict__ bias, const float* __restrict__ stats,
        const float* __restrict__ g, const float* __restrict__ be, float invN,
        unsigned short* __restrict__ out16, float* __restrict__ st_out, int N) {
    __shared__ float tb[64 * TS];
    __shared__ float st_part[128];
    __shared__ float scs[EMB], shs[EMB];
    const int tid = threadIdx.x;
    const int lane = tid & 63;
    const int wv = tid >> 6;
    const int node0 = blockIdx.x * 64;
    const int m = lane & 15;
    const int quad = lane >> 4;

    if (DO_STATS && tid < 128) st_part[tid] = 0.f;
    if (INMODE == IN_BF16BN) {
        if (tid < EMB) {
            float s1 = 0.f, s2 = 0.f;
#pragma unroll
            for (int k = 0; k < 8; k++) {
                s1 += stats[k * 128 + tid];
                s2 += stats[k * 128 + 64 + tid];
            }
            float mm = s1 * invN;
            float va = fmaf(s2, invN, -mm * mm);
            float rs = rsqrtf(va + BN_EPS);
            float sc = rs * g[tid];
            scs[tid] = sc;
            shs[tid] = fmaf(-mm, sc, be[tid]);
        }
        __syncthreads();
    }

    // A fragments (2 K-steps); invalid rows -> 0
    const int arow = node0 + wv * 16 + m;
    bfrag a0 = {0, 0, 0, 0, 0, 0, 0, 0}, a1 = {0, 0, 0, 0, 0, 0, 0, 0};
    if (arow < N) {
        if (INMODE == IN_BF16) {
            const unsigned short* ab =
                (const unsigned short*)in_v + (size_t)arow * EMB + quad * 8;
            a0 = *(const bfrag*)ab;
            a1 = *(const bfrag*)(ab + 32);
        } else if (INMODE == IN_BF16BN) {
            const unsigned short* ab =
                (const unsigned short*)in_v + (size_t)arow * EMB + quad * 8;
            bfrag r0 = *(const bfrag*)ab;
            bfrag r1 = *(const bfrag*)(ab + 32);
#pragma unroll
            for (int j = 0; j < 8; j++) {
                int k0 = quad * 8 + j;
                float v0 = b2f((unsigned short)r0[j]);
                float v1 = b2f((unsigned short)r1[j]);
                v0 = fmaxf(0.f, fmaf(v0, scs[k0], shs[k0]));
                v1 = fmaxf(0.f, fmaf(v1, scs[k0 + 32], shs[k0 + 32]));
                a0[j] = (short)f2b(v0);
                a1[j] = (short)f2b(v1);
            }
        } else {   // IN_F32
            const float* af = (const float*)in_v + (size_t)arow * EMB + quad * 8;
#pragma unroll
            for (int j = 0; j < 8; j++) {
                a0[j] = (short)f2b(af[j]);
                a1[j] = (short)f2b(af[32 + j]);
            }
        }
    }

    // B fragments from transposed bf16 weights (L2-hot) + MFMA
    const unsigned short* bb = Wt + (size_t)m * EMB + quad * 8;
    f32x4 acc[4];
#pragma unroll
    for (int c = 0; c < 4; c++) {
        bfrag b0 = *(const bfrag*)(bb + c * 16 * EMB);
        bfrag b1 = *(const bfrag*)(bb + c * 16 * EMB + 32);
        f32x4 z = {0.f, 0.f, 0.f, 0.f};
        z = __builtin_amdgcn_mfma_f32_16x16x32_bf16(a0, b0, z, 0, 0, 0);
        z = __builtin_amdgcn_mfma_f32_16x16x32_bf16(a1, b1, z, 0, 0, 0);
        acc[c] = z;
    }

    // epilogue: bias + fp32 LDS tile (invalid rows -> 0 so stats stay clean)
#pragma unroll
    for (int c = 0; c < 4; c++) {
        float bj = bias[c * 16 + m];
#pragma unroll
        for (int r = 0; r < 4; r++) {
            int row = wv * 16 + quad * 4 + r;
            float v = (node0 + row < N) ? (acc[c][r] + bj) : 0.f;
            tb[row * TS + c * 16 + m] = v;
        }
    }
    __syncthreads();

    if (DO_STATS) {
        float ssum = 0.f, ssq = 0.f;
#pragma unroll
        for (int i = 0; i < 16; i++) {
            float v = tb[(wv * 16 + i) * TS + lane];
            ssum += v;
            ssq = fmaf(v, v, ssq);
        }
        atomicAdd(&st_part[lane], ssum);
        atomicAdd(&st_part[64 + lane], ssq);
    }

    // coalesced bf16 flush: 1024 ushort4 per tile
    ushort4* o4 = (ushort4*)(out16 + (size_t)node0 * EMB);
#pragma unroll
    for (int it = 0; it < 4; it++) {
        int flat4 = it * 256 + tid;
        int nsub = flat4 >> 4;
        int c4 = flat4 & 15;
        if (node0 + nsub < N) {
            const float* s4 = tb + nsub * TS + c4 * 4;
            ushort4 o;
            o.x = f2b(s4[0]); o.y = f2b(s4[1]);
            o.z = f2b(s4[2]); o.w = f2b(s4[3]);
            o4[flat4] = o;
        }
    }

    if (DO_STATS) {
        __syncthreads();
        if (tid < 128)
            atomicAdd(&st_out[((unsigned)blockIdx.x & 7u) * 128 + tid], st_part[tid]);
    }
}

// ---------------- outer BN + relu + residual ------------------------------
// !LAST: hb16 <- bf16(relu(bn(u)) + h)   (in place over hb16)
//  LAST: out32 <- relu(bn(u)) + h        (fp32 d_out)
template <bool LAST>
__global__ void k_bnres(const unsigned short* __restrict__ u16,
                        const float* __restrict__ st,
                        const float* __restrict__ g, const float* __restrict__ be,
                        unsigned short* __restrict__ hb16, float* __restrict__ out32,
                        float invN, int total4) {
    __shared__ float scs[EMB], shs[EMB];
    const int tid = threadIdx.x;
    if (tid < EMB) {
        float s1 = 0.f, s2 = 0.f;
#pragma unroll
        for (int k = 0; k < 8; k++) {
            s1 += st[k * 128 + tid];
            s2 += st[k * 128 + 64 + tid];
        }
        float mm = s1 * invN;
        float va = fmaf(s2, invN, -mm * mm);
        float rs = rsqrtf(va + BN_EPS);
        float sc = rs * g[tid];
        scs[tid] = sc;
        shs[tid] = fmaf(-mm, sc, be[tid]);
    }
    __syncthreads();
    int stride = gridDim.x * blockDim.x;
    for (int i4 = blockIdx.x * blockDim.x + tid; i4 < total4; i4 += stride) {
        int c4 = i4 & 15;
        ushort4 uv = ((const ushort4*)u16)[i4];
        ushort4 hv = ((const ushort4*)hb16)[i4];
        float4 scv = *(const float4*)&scs[c4 * 4];
        float4 shv = *(const float4*)&shs[c4 * 4];
        float4 o;
        o.x = fmaxf(0.f, fmaf(b2f(uv.x), scv.x, shv.x)) + b2f(hv.x);
        o.y = fmaxf(0.f, fmaf(b2f(uv.y), scv.y, shv.y)) + b2f(hv.y);
        o.z = fmaxf(0.f, fmaf(b2f(uv.z), scv.z, shv.z)) + b2f(hv.z);
        o.w = fmaxf(0.f, fmaf(b2f(uv.w), scv.w, shv.w)) + b2f(hv.w);
        if (LAST) {
            ((float4*)out32)[i4] = o;
        } else {
            ushort4 ob;
            ob.x = f2b(o.x); ob.y = f2b(o.y);
            ob.z = f2b(o.z); ob.w = f2b(o.w);
            ((ushort4*)hb16)[i4] = ob;
        }
    }
}

// ---------------- launcher ----------------
extern "C" void kernel_launch(void* const* d_in, const int* in_sizes, int n_in,
                              void* d_out, int out_size, void* d_ws, size_t ws_size,
                              hipStream_t stream) {
    const float* x     = (const float*)d_in[0];
    const int*   ei    = (const int*)d_in[1];
    const float* ew    = (const float*)d_in[3];
    const float* ae_w  = (const float*)d_in[4];
    const float* ae_b  = (const float*)d_in[5];
    const float* W1    = (const float*)d_in[6];
    const float* b1    = (const float*)d_in[7];
    const float* g1    = (const float*)d_in[8];
    const float* be1   = (const float*)d_in[9];
    const float* W2    = (const float*)d_in[10];
    const float* b2    = (const float*)d_in[11];
    const float* g_out = (const float*)d_in[12];
    const float* be_out= (const float*)d_in[13];

    const int N = in_sizes[0] / EMB;
    const int E = in_sizes[3];
    const int L = in_sizes[6] / (EMB * EMB);
    const float invN = 1.0f / (float)N;
    const int NBUCK = (N + 255) >> BSH;

    uintptr_t p = (uintptr_t)d_ws;
    auto alloc = [&](size_t bytes) -> void* {
        p = (p + 255) & ~(uintptr_t)255;
        void* r = (void*)p;
        p += bytes;
        return r;
    };
    unsigned short* hb16 = (unsigned short*)alloc((size_t)N * EMB * 2); // residual h
    unsigned short* b16a = (unsigned short*)alloc((size_t)N * EMB * 2); // agg16 / u16
    unsigned short* t16  = (unsigned short*)alloc((size_t)N * EMB * 2); // t
    unsigned short* Wt16 = (unsigned short*)alloc((size_t)(1 + 2 * L) * EMB * EMB * 2);
    int*   counts= (int*)alloc((size_t)N * 4);
    int*   rowst = (int*)alloc((size_t)N * 4);
    int*   hist_part = (int*)alloc((size_t)NHB * 256 * 4);
    int*   bbase = (int*)alloc(257 * 4);
    int*   bcur  = (int*)alloc(256 * 4);
    int2*  pairs = (int2*)alloc((size_t)E * 8);
    int2*  eG    = (int2*)alloc((size_t)E * 8);
    float* stats = (float*)alloc((size_t)L * 2 * 8 * 128 * 4);
    (void)ws_size; (void)n_in; (void)out_size;

    // prep: weights -> transposed bf16, zero stats, hist partials (atomic-free)
    const int nw = (1 + 2 * L) * EMB * EMB;
    const int nstats = L * 2 * 8 * 128;
    const int nprep = (nw + 255) / 256;            // 144 blocks >= NHB
    hipLaunchKernelGGL(k_prep_hist, dim3(nprep > NHB ? nprep : NHB), dim3(256), 0,
                       stream, ae_w, W1, W2, Wt16, hist_part, stats, ei, E, L, nstats);

    const int ntiles = (N + 63) / 64;
    // encoder: hb16 = bf16(x @ ae_w + ae_b)
    hipLaunchKernelGGL((k_mmx<IN_F32, false>), dim3(ntiles), dim3(256), 0, stream,
                       x, Wt16, ae_b, (const float*)nullptr, (const float*)nullptr,
                       (const float*)nullptr, 0.f, hb16, (float*)nullptr, N);

    // CSR build: scan -> compact -> per-bucket exact CSR
    hipLaunchKernelGGL(k_bscan, dim3(1), dim3(256), 0, stream,
                       hist_part, bbase, bcur, NBUCK);
    hipLaunchKernelGGL(k_part, dim3((E + CHUNK - 1) / CHUNK), dim3(256), 0, stream,
                       ei, ew, bcur, eG, E);
    hipLaunchKernelGGL(k_build, dim3(NBUCK), dim3(256), 0, stream,
                       eG, bbase, rowst, counts, pairs, N);

    for (int l = 0; l < L; l++) {
        float* stats1 = stats + (size_t)(l * 2 + 0) * 1024;
        float* stats2 = stats + (size_t)(l * 2 + 1) * 1024;

        // agg + self -> bf16 (mm1's A operand), 16-deep gather ILP
        hipLaunchKernelGGL(k_agg, dim3(2048), dim3(256), 0, stream,
                           hb16, rowst, counts, pairs, b16a, N);
        // t16 = bf16(agg @ W1 + b1)   (+stats1, fp32-exact, 8-way spread)
        hipLaunchKernelGGL((k_mmx<IN_BF16, true>), dim3(ntiles), dim3(256), 0, stream,
                           b16a, Wt16 + (size_t)(1 + l) * EMB * EMB, b1 + (size_t)l * EMB,
                           (const float*)nullptr, (const float*)nullptr,
                           (const float*)nullptr, 0.f, t16, stats1, N);
        // u16 = bf16(relu(bn1(t)) @ W2 + b2)   (BN fused, +stats2)
        hipLaunchKernelGGL((k_mmx<IN_BF16BN, true>), dim3(ntiles), dim3(256), 0, stream,
                           t16, Wt16 + (size_t)(1 + L + l) * EMB * EMB, b2 + (size_t)l * EMB,
                           stats1, g1 + (size_t)l * EMB, be1 + (size_t)l * EMB, invN,
                           b16a, stats2, N);
        // h = relu(bn2(u)) + h   (in-place hb16; last layer -> fp32 d_out)
        if (l == L - 1) {
            hipLaunchKernelGGL((k_bnres<true>), dim3(1024), dim3(256), 0, stream,
                               b16a, stats2, g_out + (size_t)l * EMB,
                               be_out + (size_t)l * EMB, hb16, (float*)d_out,
                               invN, N * 16);
        } else {
            hipLaunchKernelGGL((k_bnres<false>), dim3(1024), dim3(256), 0, stream,
                               b16a, stats2, g_out + (size_t)l * EMB,
                               be_out + (size_t)l * EMB, hb16, (float*)nullptr,
                               invN, N * 16);
        }
    }
}